// Round 10
// baseline (180.946 us; speedup 1.0000x reference)
//
#include <hip/hip_runtime.h>
#include <hip/hip_bf16.h>

#define SGQ 4096
#define DMODEL 512
#define NH 8
#define DHEAD 64

typedef __attribute__((ext_vector_type(8))) short s16x8;
typedef __attribute__((ext_vector_type(4))) float f32x4;
typedef __attribute__((ext_vector_type(16))) float f32x16;
typedef __attribute__((ext_vector_type(4))) unsigned int u32x4;

__device__ inline ushort f2bf(float x) {
  unsigned u = __float_as_uint(x);
  return (ushort)((u + 0x7FFFu + ((u >> 16) & 1u)) >> 16);
}
__device__ inline float bf2f(ushort h) { return __uint_as_float(((unsigned)h) << 16); }
__device__ inline float exp2_hw(float x) {  // v_exp_f32 computes 2^x
  float r; asm("v_exp_f32 %0, %1" : "=v"(r) : "v"(x)); return r;
}
__device__ inline void gload16(const ushort* g, ushort* l) {
  __builtin_amdgcn_global_load_lds((const __attribute__((address_space(1))) void*)g,
                                   (__attribute__((address_space(3))) void*)l, 16, 0, 0);
}
// row->granule swizzles: each consecutive-8-lane group hits 8 distinct bank-quads
#define SWX(row) (((row) & 7) ^ (((row) >> 1) & 4))
#define S16(row) ((row) & 15)

// ================= merged prep: 9x weight convert/transpose + LayerNorm both sides ========
struct PArgs {
  const float* w[9]; ushort* wt[9]; int K[9];
  const float* x[2]; const float* gg[2]; const float* bb[2];
  ushort* normed[2]; ushort* cat[2];
};

__global__ __launch_bounds__(256) void prep_kernel(PArgs args) {
  int z = blockIdx.z;
  if (z < 9) {
    __shared__ float tile[32][33];
    int K = args.K[z];
    int k0 = blockIdx.y * 32;
    if (k0 >= K) return;
    const float* W = args.w[z];
    ushort* Wt = args.wt[z];
    int n0 = blockIdx.x * 32;
    int tx = threadIdx.x & 31, ty = threadIdx.x >> 5;
    #pragma unroll
    for (int i = ty; i < 32; i += 8) tile[i][tx] = W[(size_t)(k0 + i) * DMODEL + n0 + tx];
    __syncthreads();
    #pragma unroll
    for (int i = ty; i < 32; i += 8) Wt[(size_t)(n0 + i) * K + k0 + tx] = f2bf(tile[tx][i]);
  } else {
    int side = z - 9;
    int flat = blockIdx.x + (blockIdx.y << 4);   // [0,512)
    int lane = threadIdx.x & 63;
    const float* g = args.gg[side];
    const float* b = args.bb[side];
    #pragma unroll
    for (int pass = 0; pass < 2; ++pass) {
      int row = flat * 8 + pass * 4 + (threadIdx.x >> 6);
      const float* xr = args.x[side] + (size_t)row * DMODEL + lane * 8;
      float4 p0 = *(const float4*)xr;
      float4 p1 = *(const float4*)(xr + 4);
      float v[8] = {p0.x, p0.y, p0.z, p0.w, p1.x, p1.y, p1.z, p1.w};
      float s = 0.f;
      #pragma unroll
      for (int j = 0; j < 8; ++j) s += v[j];
      #pragma unroll
      for (int m = 1; m <= 32; m <<= 1) s += __shfl_xor(s, m);
      float mu = s * (1.0f / DMODEL);
      float q = 0.f;
      #pragma unroll
      for (int j = 0; j < 8; ++j) { float d = v[j] - mu; q += d * d; }
      #pragma unroll
      for (int m = 1; m <= 32; m <<= 1) q += __shfl_xor(q, m);
      float rs = rsqrtf(q * (1.0f / DMODEL) + 1e-5f);
      s16x8 nout, eout;
      #pragma unroll
      for (int j = 0; j < 8; ++j) {
        int c = lane * 8 + j;
        nout[j] = (short)f2bf((v[j] - mu) * rs * g[c] + b[c]);
        eout[j] = (short)f2bf(v[j]);
      }
      *(s16x8*)(args.normed[side] + (size_t)row * DMODEL + lane * 8) = nout;
      *(s16x8*)(args.cat[side] + (size_t)row * 1024 + DMODEL + lane * 8) = eout;
    }
  }
}

// ================= fused final: out = emb + sigmoid(LN(tmpF)) * tmpY (both sides) =========
struct FArgs {
  const float* tF[2]; const float* tY[2]; const float* emb[2];
  const float* gamma[2]; const float* beta[2]; float* out[2];
};

__global__ __launch_bounds__(256) void ln_sig_combine_kernel(FArgs args) {
  int side = blockIdx.y;
  int row = blockIdx.x * 4 + (threadIdx.x >> 6);
  int lane = threadIdx.x & 63;
  size_t base = (size_t)row * DMODEL + lane * 8;
  const float* xr = args.tF[side] + base;
  float4 p0 = *(const float4*)xr;
  float4 p1 = *(const float4*)(xr + 4);
  float v[8] = {p0.x, p0.y, p0.z, p0.w, p1.x, p1.y, p1.z, p1.w};
  float s = 0.f;
  #pragma unroll
  for (int j = 0; j < 8; ++j) s += v[j];
  #pragma unroll
  for (int m = 1; m <= 32; m <<= 1) s += __shfl_xor(s, m);
  float mu = s * (1.0f / DMODEL);
  float q = 0.f;
  #pragma unroll
  for (int j = 0; j < 8; ++j) { float d = v[j] - mu; q += d * d; }
  #pragma unroll
  for (int m = 1; m <= 32; m <<= 1) q += __shfl_xor(q, m);
  float rs = rsqrtf(q * (1.0f / DMODEL) + 1e-5f);
  const float* g = args.gamma[side];
  const float* b = args.beta[side];
  float4 y0 = *(const float4*)(args.tY[side] + base);
  float4 y1 = *(const float4*)(args.tY[side] + base + 4);
  float4 e0 = *(const float4*)(args.emb[side] + base);
  float4 e1 = *(const float4*)(args.emb[side] + base + 4);
  float yv[8] = {y0.x, y0.y, y0.z, y0.w, y1.x, y1.y, y1.z, y1.w};
  float ev[8] = {e0.x, e0.y, e0.z, e0.w, e1.x, e1.y, e1.z, e1.w};
  float ov[8];
  #pragma unroll
  for (int j = 0; j < 8; ++j) {
    int c = lane * 8 + j;
    float y = (v[j] - mu) * rs * g[c] + b[c];
    float gate = 1.0f / (1.0f + __expf(-y));
    ov[j] = ev[j] + gate * yv[j];
  }
  float4 o0 = {ov[0], ov[1], ov[2], ov[3]};
  float4 o1 = {ov[4], ov[5], ov[6], ov[7]};
  *(float4*)(args.out[side] + base) = o0;
  *(float4*)(args.out[side] + base + 4) = o1;
}

// ================= unified 128x128-tile GEMM, global_load_lds staging (m97 structure) =====
struct GemmDesc {
  const ushort* A; const ushort* Wt; const float* bias;
  void* dst; const float* emb; const ushort* gate;
  int lda; int K; float scale; int isV;
};
struct GemmArgs { GemmDesc d[6]; };

template <int EPI>
__global__ __launch_bounds__(256, 2) void gemm_tiled(GemmArgs args) {
  __shared__ __align__(16) ushort Ash[2][128 * 32];
  __shared__ __align__(16) ushort Bsh[2][128 * 32];
  const GemmDesc& D = args.d[blockIdx.z];
  const int tid = threadIdx.x;
  const int w = tid >> 6, lane = tid & 63;
  const int ln = lane & 15, g = lane >> 4;
  const int wr = w >> 1, wc = w & 1;
  const int rowT = blockIdx.y * 128, colT = blockIdx.x * 128;
  const int K = D.K, lda = D.lda;
  const int srow = lane >> 2, scol = (lane & 3) * 8;

  f32x4 zero = {0.f, 0.f, 0.f, 0.f};
  f32x4 acc[4][4];
  #pragma unroll
  for (int m = 0; m < 4; ++m)
    #pragma unroll
    for (int n = 0; n < 4; ++n) acc[m][n] = zero;

  auto stage = [&](int cur, int k0) {
    #pragma unroll
    for (int c = 0; c < 2; ++c) {
      const int rbase = c * 64 + w * 16;
      gload16(D.A + (size_t)(rowT + rbase + srow) * lda + k0 + scol, &Ash[cur][rbase * 32]);
      gload16(D.Wt + (size_t)(colT + rbase + srow) * K + k0 + scol, &Bsh[cur][rbase * 32]);
    }
  };

  stage(0, 0);
  const int nT = K >> 5;
  for (int t = 0; t < nT; ++t) {
    const int cur = t & 1;
    __syncthreads();
    if (t + 1 < nT) stage(cur ^ 1, (t + 1) * 32);
    s16x8 af[4], bf[4];
    #pragma unroll
    for (int m = 0; m < 4; ++m) {
      af[m] = *(const s16x8*)&Ash[cur][(wr * 64 + m * 16 + ln) * 32 + g * 8];
      bf[m] = *(const s16x8*)&Bsh[cur][(wc * 64 + m * 16 + ln) * 32 + g * 8];
    }
    #pragma unroll
    for (int m = 0; m < 4; ++m)
      #pragma unroll
      for (int n = 0; n < 4; ++n)
        acc[m][n] = __builtin_amdgcn_mfma_f32_16x16x32_bf16(af[m], bf[n], acc[m][n], 0, 0, 0);
  }

  const float* bias = D.bias;
  const int colw = colT + wc * 64;
  if (EPI == 0) {
    const int h = colw >> 6;
    if (!D.isV) {
      float sc[4][4];
      #pragma unroll
      for (int m = 0; m < 4; ++m) {
        float ss[4] = {0.f, 0.f, 0.f, 0.f};
        #pragma unroll
        for (int n = 0; n < 4; ++n) {
          float bv = bias[colw + n * 16 + ln];
          #pragma unroll
          for (int r = 0; r < 4; ++r) {
            float v = acc[m][n][r] + bv;
            acc[m][n][r] = v;
            ss[r] += v * v;
          }
        }
        #pragma unroll
        for (int r = 0; r < 4; ++r) {
          float v = ss[r];
          v += __shfl_xor(v, 1); v += __shfl_xor(v, 2);
          v += __shfl_xor(v, 4); v += __shfl_xor(v, 8);
          sc[m][r] = D.scale / fmaxf(sqrtf(v), 1e-12f);
        }
      }
      ushort* dst = (ushort*)D.dst;
      #pragma unroll
      for (int m = 0; m < 4; ++m)
        #pragma unroll
        for (int n = 0; n < 4; ++n)
          #pragma unroll
          for (int r = 0; r < 4; ++r) {
            int row = rowT + wr * 64 + m * 16 + g * 4 + r;
            dst[((size_t)h * SGQ + row) * DHEAD + n * 16 + ln] = f2bf(acc[m][n][r] * sc[m][r]);
          }
    } else {
      ushort* dst = (ushort*)D.dst;
      #pragma unroll
      for (int m = 0; m < 4; ++m)
        #pragma unroll
        for (int n = 0; n < 4; ++n) {
          int d = n * 16 + ln;
          float bv = bias[colw + d];
          uint lo = (uint)f2bf(acc[m][n][0] + bv) | ((uint)f2bf(acc[m][n][1] + bv) << 16);
          uint hi2 = (uint)f2bf(acc[m][n][2] + bv) | ((uint)f2bf(acc[m][n][3] + bv) << 16);
          int s0 = rowT + wr * 64 + m * 16 + g * 4;
          uint2 pk; pk.x = lo; pk.y = hi2;
          *(uint2*)(dst + (size_t)(h * DHEAD + d) * SGQ + s0) = pk;
        }
    }
  } else {
    float* outF = (float*)D.dst;
    #pragma unroll
    for (int m = 0; m < 4; ++m)
      #pragma unroll
      for (int n = 0; n < 4; ++n) {
        float bv = bias[colw + n * 16 + ln];
        #pragma unroll
        for (int r = 0; r < 4; ++r)
          outF[(size_t)(rowT + wr * 64 + m * 16 + g * 4 + r) * DMODEL + colw + n * 16 + ln] =
              acc[m][n][r] + bv;
      }
  }
}

// ================= attention shared args =================================================
struct AArgs {
  const ushort* qn[2]; const ushort* kn[2]; const ushort* vt[2]; ushort* cat[2];
  float* oPart; float* rsPart;
};

// ---------- fallback (R9): KVBLK=128, direct output ----------
__global__ __launch_bounds__(256, 2) void attn_kernel128(AArgs args) {
  __shared__ __align__(16) ushort Ksh[2][128 * 64];
  __shared__ __align__(16) ushort Vsh[2][64 * 128];
  const int side = blockIdx.z, h = blockIdx.y, qb = blockIdx.x;
  const int w = threadIdx.x >> 6, lane = threadIdx.x & 63;
  const int l32 = lane & 31, hi = lane >> 5;
  const int l8 = lane & 7, lr = lane >> 3;
  const ushort* qnh = args.qn[side] + (size_t)h * SGQ * DHEAD;
  const ushort* knh = args.kn[side] + (size_t)h * SGQ * DHEAD;
  const ushort* vth = args.vt[side] + (size_t)h * DHEAD * SGQ;
  ushort* cat = args.cat[side];
  const int r0w = qb * 128 + w * 32;

  s16x8 qf[4];
  #pragma unroll
  for (int s = 0; s < 4; ++s)
    qf[s] = *(const s16x8*)(qnh + (size_t)(r0w + l32) * DHEAD + s * 16 + hi * 8);

  s16x8 sk[4], sv[2][2];
  auto prefetch = [&](int key0) {
    #pragma unroll
    for (int c = 0; c < 4; ++c) {
      int row = w * 32 + c * 8 + lr;
      sk[c] = *(const s16x8*)(knh + (size_t)(key0 + row) * DHEAD + l8 * 8);
    }
    #pragma unroll
    for (int c = 0; c < 2; ++c) {
      int vrow = w * 16 + c * 8 + lr;
      #pragma unroll
      for (int half = 0; half < 2; ++half)
        sv[c][half] = *(const s16x8*)(vth + (size_t)vrow * SGQ + key0 + (l8 + 8 * half) * 8);
    }
  };

  const f32x16 Z = {0,0,0,0,0,0,0,0,0,0,0,0,0,0,0,0};
  f32x16 o0 = Z, o1 = Z;
  float rs0 = 0.f, rs1 = 0.f;
  const int krp = (l32 & 19) | ((l32 & 4) << 1) | ((l32 & 8) >> 1);  // swap bits 2<->3

  auto body = [&](int buf, int t) {
    #pragma unroll
    for (int c = 0; c < 4; ++c) {
      int row = w * 32 + c * 8 + lr;
      *(s16x8*)&Ksh[buf][row * 64 + ((l8 ^ SWX(row)) * 8)] = sk[c];
    }
    #pragma unroll
    for (int c = 0; c < 2; ++c) {
      int vrow = w * 16 + c * 8 + lr;
      #pragma unroll
      for (int half = 0; half < 2; ++half)
        *(s16x8*)&Vsh[buf][vrow * 128 + (((l8 + 8 * half) ^ S16(vrow)) * 8)] = sv[c][half];
    }
    asm volatile("s_waitcnt lgkmcnt(0)" ::: "memory");
    __builtin_amdgcn_s_barrier();
    asm volatile("" ::: "memory");
    if (t != 31) prefetch((t + 1) << 7);
    #pragma unroll
    for (int st = 0; st < 4; ++st) {
      const int kr = st * 32 + krp;
      const int rsw = SWX(kr);
      s16x8 ka[4];
      #pragma unroll
      for (int s = 0; s < 4; ++s)
        ka[s] = *(const s16x8*)&Ksh[buf][kr * 64 + (((s * 2 + hi) ^ rsw) * 8)];
      f32x16 S = Z;
      __builtin_amdgcn_s_setprio(1);
      #pragma unroll
      for (int s = 0; s < 4; ++s)
        S = __builtin_amdgcn_mfma_f32_32x32x16_bf16(ka[s], qf[s], S, 0, 0, 0);
      __builtin_amdgcn_s_setprio(0);
      #pragma unroll
      for (int i = 0; i < 16; ++i) S[i] = exp2_hw(S[i]);
      #pragma unroll
      for (int i = 0; i < 16; i += 2) { rs0 += S[i]; rs1 += S[i + 1]; }
      uint u[8];
      #pragma unroll
      for (int j2 = 0; j2 < 8; ++j2) {
        uint r_;
        asm("v_cvt_pk_bf16_f32 %0, %1, %2" : "=v"(r_) : "v"(S[2 * j2]), "v"(S[2 * j2 + 1]));
        u[j2] = r_;
      }
      __builtin_amdgcn_s_setprio(1);
      #pragma unroll
      for (int slot = 0; slot < 2; ++slot) {
        u32x4 uv = {u[slot * 4 + 0], u[slot * 4 + 1], u[slot * 4 + 2], u[slot * 4 + 3]};
        s16x8 pf = __builtin_bit_cast(s16x8, uv);
        const int kcg = st * 4 + slot * 2 + hi;
        {
          const int vr = l32;
          s16x8 vb = *(const s16x8*)&Vsh[buf][vr * 128 + ((kcg ^ S16(vr)) * 8)];
          o0 = __builtin_amdgcn_mfma_f32_32x32x16_bf16(pf, vb, o0, 0, 0, 0);
        }
        {
          const int vr = 32 + l32;
          s16x8 vb = *(const s16x8*)&Vsh[buf][vr * 128 + ((kcg ^ S16(vr)) * 8)];
          o1 = __builtin_amdgcn_mfma_f32_32x32x16_bf16(pf, vb, o1, 0, 0, 0);
        }
      }
      __builtin_amdgcn_s_setprio(0);
    }
  };

  prefetch(0);
  for (int tt = 0; tt < 16; ++tt) {
    body(0, tt * 2);
    body(1, tt * 2 + 1);
  }

  float rsum = rs0 + rs1;
  rsum += __shfl_xor(rsum, 32);
  float invq = 1.0f / rsum;
  #pragma unroll
  for (int r = 0; r < 16; ++r) {
    const int qr = (r & 3) + 8 * (r >> 2) + 4 * hi;
    float inv = __shfl(invq, qr);
    size_t base = (size_t)(r0w + qr) * 1024 + h * DHEAD + l32;
    cat[base] = f2bf(o0[r] * inv);
    cat[base + 32] = f2bf(o1[r] * inv);
  }
}

// ---------- key-split (R8 body): KVBLK=64, each block does 2048 keys, partial output ------
__global__ __launch_bounds__(256) void attn_split_kernel(AArgs args) {
  __shared__ __align__(16) ushort Ksh[2][64 * 64];
  __shared__ __align__(16) ushort Vsh[2][64 * 64];
  const int side = blockIdx.z, qb = blockIdx.x;
  const int h = blockIdx.y & 7, split = blockIdx.y >> 3;
  const int kbase = split * (SGQ / 2);
  const int w = threadIdx.x >> 6, lane = threadIdx.x & 63;
  const int l32 = lane & 31, hi = lane >> 5;
  const int l8 = lane & 7, lr = lane >> 3;
  const ushort* qnh = args.qn[side] + (size_t)h * SGQ * DHEAD;
  const ushort* knh = args.kn[side] + (size_t)h * SGQ * DHEAD;
  const ushort* vth = args.vt[side] + (size_t)h * DHEAD * SGQ;
  const int r0w = qb * 128 + w * 32;

  s16x8 qf[4];
  #pragma unroll
  for (int s = 0; s < 4; ++s)
    qf[s] = *(const s16x8*)(qnh + (size_t)(r0w + l32) * DHEAD + s * 16 + hi * 8);

  const int krow0 = w * 16;  // this wave stages K/V rows [krow0, krow0+16) of each tile
  s16x8 sk[2], sv[2];
  #pragma unroll
  for (int c = 0; c < 2; ++c) {
    int row = krow0 + c * 8 + lr;
    sk[c] = *(const s16x8*)(knh + (size_t)(kbase + row) * DHEAD + l8 * 8);
    sv[c] = *(const s16x8*)(vth + (size_t)row * SGQ + kbase + l8 * 8);
  }

  const f32x16 Z = {0,0,0,0,0,0,0,0,0,0,0,0,0,0,0,0};
  f32x16 o0 = Z, o1 = Z;
  float rs0 = 0.f, rs1 = 0.f;
  const int krp = (l32 & 19) | ((l32 & 4) << 1) | ((l32 & 8) >> 1);  // swap bits 2<->3

  for (int t = 0; t < 32; ++t) {
    const int cur = t & 1;
    #pragma unroll
    for (int c = 0; c < 2; ++c) {
      int row = krow0 + c * 8 + lr;
      int colsw = (l8 ^ SWX(row)) * 8;
      *(s16x8*)&Ksh[cur][row * 64 + colsw] = sk[c];
      *(s16x8*)&Vsh[cur][row * 64 + colsw] = sv[c];
    }
    asm volatile("s_waitcnt lgkmcnt(0)" ::: "memory");
    __builtin_amdgcn_s_barrier();
    asm volatile("" ::: "memory");
    if (t < 31) {
      const int key0 = kbase + ((t + 1) << 6);
      #pragma unroll
      for (int c = 0; c < 2; ++c) {
        int row = krow0 + c * 8 + lr;
        sk[c] = *(const s16x8*)(knh + (size_t)(key0 + row) * DHEAD + l8 * 8);
        sv[c] = *(const s16x8*)(vth + (size_t)row * SGQ + key0 + l8 * 8);
      }
    }
    #pragma unroll
    for (int st = 0; st < 2; ++st) {
      const int kr = st * 32 + krp;
      const int rsw = SWX(kr);
      s16x8 ka[4];
      #pragma unroll
      for (int s = 0; s < 4; ++s)
        ka[s] = *(const s16x8*)&Ksh[cur][kr * 64 + (((s * 2 + hi) ^ rsw) * 8)];
      f32x16 S = Z;
      __builtin_amdgcn_s_setprio(1);
      #pragma unroll
      for (int s = 0; s < 4; ++s)
        S = __builtin_amdgcn_mfma_f32_32x32x16_bf16(ka[s], qf[s], S, 0, 0, 0);
      __builtin_amdgcn_s_setprio(0);
      #pragma unroll
      for (int i = 0; i < 16; ++i) S[i] = exp2_hw(S[i]);
      #pragma unroll
      for (int i = 0; i < 16; i += 2) { rs0 += S[i]; rs1 += S[i + 1]; }
      uint u[8];
      #pragma unroll
      for (int j2 = 0; j2 < 8; ++j2) {
        uint r_;
        asm("v_cvt_pk_bf16_f32 %0, %1, %2" : "=v"(r_) : "v"(S[2 * j2]), "v"(S[2 * j2 + 1]));
        u[j2] = r_;
      }
      __builtin_amdgcn_s_setprio(1);
      #pragma unroll
      for (int slot = 0; slot < 2; ++slot) {
        u32x4 uv = {u[slot * 4 + 0], u[slot * 4 + 1], u[slot * 4 + 2], u[slot * 4 + 3]};
        s16x8 pf = __builtin_bit_cast(s16x8, uv);
        const int kcg = st * 4 + slot * 2 + hi;
        {
          const int vr = l32;
          s16x8 vb = *(const s16x8*)&Vsh[cur][vr * 64 + ((kcg ^ SWX(vr)) * 8)];
          o0 = __builtin_amdgcn_mfma_f32_32x32x16_bf16(pf, vb, o0, 0, 0, 0);
        }
        {
          const int vr = 32 + l32;
          s16x8 vb = *(const s16x8*)&Vsh[cur][vr * 64 + ((kcg ^ SWX(vr)) * 8)];
          o1 = __builtin_amdgcn_mfma_f32_32x32x16_bf16(pf, vb, o1, 0, 0, 0);
        }
      }
      __builtin_amdgcn_s_setprio(0);
    }
  }
  float rsum = rs0 + rs1;
  rsum += __shfl_xor(rsum, 32);
  // partial write: unnormalized o (f32) + rowsum
  const int combo = side * 8 + h;
  float* oP = args.oPart + ((size_t)(split * 16 + combo) * SGQ) * 64;
  #pragma unroll
  for (int r = 0; r < 16; ++r) {
    const int qr = (r & 3) + 8 * (r >> 2) + 4 * hi;
    size_t base = (size_t)(r0w + qr) * 64 + l32;
    oP[base] = o0[r];
    oP[base + 32] = o1[r];
  }
  if (hi == 0)
    args.rsPart[(size_t)(split * 16 + combo) * SGQ + r0w + l32] = rsum;
}

// ---------- combine partials -> cat ----------
struct CArgs { const float* oP; const float* rsP; ushort* cat[2]; };

__global__ __launch_bounds__(256) void attn_combine_kernel(CArgs args) {
  const int c = blockIdx.y, side = c >> 3, h = c & 7;
  const int idx = blockIdx.x * 256 + threadIdx.x;   // [0, 65536)
  const int d4 = idx & 15, q = idx >> 4;
  size_t b0 = ((size_t)c * SGQ + q) * 64 + d4 * 4;
  size_t b1 = ((size_t)(16 + c) * SGQ + q) * 64 + d4 * 4;
  float4 a = *(const float4*)(args.oP + b0);
  float4 b = *(const float4*)(args.oP + b1);
  float rs = args.rsP[(size_t)c * SGQ + q] + args.rsP[(size_t)(16 + c) * SGQ + q];
  float inv = 1.0f / rs;
  ushort4 w;
  w.x = f2bf((a.x + b.x) * inv);
  w.y = f2bf((a.y + b.y) * inv);
  w.z = f2bf((a.z + b.z) * inv);
  w.w = f2bf((a.w + b.w) * inv);
  *(ushort4*)(args.cat[side] + (size_t)q * 1024 + h * 64 + d4 * 4) = w;
}

// ================= host ====================================================================
extern "C" void kernel_launch(void* const* d_in, const int* in_sizes, int n_in,
                              void* d_out, int out_size, void* d_ws, size_t ws_size,
                              hipStream_t stream) {
  const float* gene = (const float*)d_in[0];
  const float* drug = (const float*)d_in[1];
  const float* lng_g = (const float*)d_in[2];
  const float* lng_b = (const float*)d_in[3];
  const float* lnd_g = (const float*)d_in[4];
  const float* lnd_b = (const float*)d_in[5];
  const float* wgq = (const float*)d_in[6];  const float* bgq = (const float*)d_in[7];
  const float* wgk = (const float*)d_in[8];  const float* bgk = (const float*)d_in[9];
  const float* wgv = (const float*)d_in[10]; const float* bgv = (const float*)d_in[11];
  const float* wdq = (const float*)d_in[12]; const float* bdq = (const float*)d_in[13];
  const float* wdk = (const float*)d_in[14]; const float* bdk = (const float*)d_in[15];
  const float* wdv = (const float*)d_in[16]; const float* bdv = (const float*)d_in[17];
  const float* wo  = (const float*)d_in[18]; const float* bo  = (const float*)d_in[19];
  const float* wgg = (const float*)d_in[20]; const float* bgg = (const float*)d_in[21];
  const float* gg_g = (const float*)d_in[22]; const float* gg_b = (const float*)d_in[23];
  const float* wdg = (const float*)d_in[24]; const float* bdg = (const float*)d_in[25];
  const float* dg_g = (const float*)d_in[26]; const float* dg_b = (const float*)d_in[27];
  float* out = (float*)d_out;

  char* p = (char*)d_ws;
  size_t off = 0;
  auto alloc = [&](size_t bytes) { char* r = p + off; off = (off + bytes + 255) & ~(size_t)255; return r; };
  ushort* wT_gq = (ushort*)alloc(512 * 512 * 2);
  ushort* wT_gk = (ushort*)alloc(512 * 512 * 2);
  ushort* wT_gv = (ushort*)alloc(512 * 512 * 2);
  ushort* wT_dq = (ushort*)alloc(512 * 512 * 2);
  ushort* wT_dk = (ushort*)alloc(512 * 512 * 2);
  ushort* wT_dv = (ushort*)alloc(512 * 512 * 2);
  ushort* wT_o  = (ushort*)alloc(512 * 512 * 2);
  ushort* wT_gg = (ushort*)alloc(1024 * 512 * 2);
  ushort* wT_dg = (ushort*)alloc(1024 * 512 * 2);
  ushort* ng   = (ushort*)alloc((size_t)SGQ * 512 * 2);   // + nd = contiguous 8 MB
  ushort* nd   = (ushort*)alloc((size_t)SGQ * 512 * 2);
  ushort* catg = (ushort*)alloc((size_t)SGQ * 1024 * 2);
  ushort* catd = (ushort*)alloc((size_t)SGQ * 1024 * 2);
  ushort* qn_g = (ushort*)alloc((size_t)SGQ * 512 * 2);   // + kn_g = contiguous 8 MB
  ushort* kn_g = (ushort*)alloc((size_t)SGQ * 512 * 2);
  ushort* qn_d = (ushort*)alloc((size_t)SGQ * 512 * 2);   // + kn_d = contiguous 8 MB
  ushort* kn_d = (ushort*)alloc((size_t)SGQ * 512 * 2);
  ushort* vt_g = (ushort*)alloc((size_t)SGQ * 512 * 2);   // + vt_d = contiguous 8 MB
  ushort* vt_d = (ushort*)alloc((size_t)SGQ * 512 * 2);
  // dead-buffer reuse after attention (qn/kn/vt dead) and after qkv (ng/nd dead):
  float* tmpF_g = (float*)qn_g;   // 8 MB f32 spans qn_g+kn_g
  float* tmpF_d = (float*)qn_d;   // 8 MB f32 spans qn_d+kn_d
  float* tmpY_g = (float*)vt_g;   // 8 MB f32 spans vt_g+vt_d
  float* tmpY_d = (float*)ng;     // 8 MB f32 spans ng+nd
  // key-split scratch (guarded by ws_size check)
  float* oPart = (float*)alloc((size_t)2 * 16 * SGQ * 64 * 4);   // 33.6 MB
  float* rsPart = (float*)alloc((size_t)2 * 16 * SGQ * 4);       // 0.5 MB
  const bool useSplit = (off <= ws_size);

  dim3 blk(256);
  const float QSCALE = 0.125f * 1.4426950408889634f;  // head-scale * log2(e)

  PArgs pa;
  {
    const float* ws_[9] = {wgq, wgk, wgv, wdq, wdk, wdv, wo, wgg, wdg};
    ushort* wt_[9] = {wT_gq, wT_gk, wT_gv, wT_dq, wT_dk, wT_dv, wT_o, wT_gg, wT_dg};
    int k_[9] = {512, 512, 512, 512, 512, 512, 512, 1024, 1024};
    for (int i = 0; i < 9; ++i) { pa.w[i] = ws_[i]; pa.wt[i] = wt_[i]; pa.K[i] = k_[i]; }
    pa.x[0] = gene; pa.x[1] = drug;
    pa.gg[0] = lng_g; pa.gg[1] = lnd_g;
    pa.bb[0] = lng_b; pa.bb[1] = lnd_b;
    pa.normed[0] = ng; pa.normed[1] = nd;
    pa.cat[0] = catg; pa.cat[1] = catd;
  }
  prep_kernel<<<dim3(16, 32, 11), blk, 0, stream>>>(pa);

  GemmArgs qa;
  {
    const ushort* A_[6] = {ng, ng, catg + 512, nd, nd, catd + 512};
    const ushort* W_[6] = {wT_gq, wT_gk, wT_gv, wT_dq, wT_dk, wT_dv};
    const float* B_[6] = {bgq, bgk, bgv, bdq, bdk, bdv};
    ushort* D_[6] = {qn_g, kn_g, vt_g, qn_d, kn_d, vt_d};
    int lda_[6] = {512, 512, 1024, 512, 512, 1024};
    float sc_[6] = {QSCALE, 1.0f, 0.f, QSCALE, 1.0f, 0.f};
    int iv_[6] = {0, 0, 1, 0, 0, 1};
    for (int i = 0; i < 6; ++i) {
      qa.d[i].A = A_[i]; qa.d[i].Wt = W_[i]; qa.d[i].bias = B_[i];
      qa.d[i].dst = D_[i]; qa.d[i].emb = nullptr; qa.d[i].gate = nullptr;
      qa.d[i].lda = lda_[i]; qa.d[i].K = 512; qa.d[i].scale = sc_[i]; qa.d[i].isV = iv_[i];
    }
  }
  gemm_tiled<0><<<dim3(4, 32, 6), blk, 0, stream>>>(qa);

  AArgs aa;
  aa.qn[0] = qn_g; aa.qn[1] = qn_d;
  aa.kn[0] = kn_d; aa.kn[1] = kn_g;   // cross: gene-q attends drug-K/V, and vice versa
  aa.vt[0] = vt_d; aa.vt[1] = vt_g;
  aa.cat[0] = catg; aa.cat[1] = catd;
  aa.oPart = oPart; aa.rsPart = rsPart;
  if (useSplit) {
    attn_split_kernel<<<dim3(32, 16, 2), blk, 0, stream>>>(aa);
    CArgs ca;
    ca.oP = oPart; ca.rsP = rsPart;
    ca.cat[0] = catg; ca.cat[1] = catd;
    attn_combine_kernel<<<dim3(256, 16), blk, 0, stream>>>(ca);
  } else {
    attn_kernel128<<<dim3(32, 8, 2), blk, 0, stream>>>(aa);
  }

  // gate pre-LN GEMM (z=0,1) and ctx@wo+bo (z=2,3) in ONE dispatch
  GemmArgs ga;
  {
    const ushort* A_[4] = {catg, catd, catg, catd};
    const ushort* W_[4] = {wT_gg, wT_dg, wT_o, wT_o};
    const float* B_[4] = {bgg, bdg, bo, bo};
    float* D_[4] = {tmpF_g, tmpF_d, tmpY_g, tmpY_d};
    int k_[4] = {1024, 1024, 512, 512};
    for (int i = 0; i < 4; ++i) {
      ga.d[i].A = A_[i]; ga.d[i].Wt = W_[i]; ga.d[i].bias = B_[i];
      ga.d[i].dst = D_[i]; ga.d[i].emb = nullptr; ga.d[i].gate = nullptr;
      ga.d[i].lda = 1024; ga.d[i].K = k_[i]; ga.d[i].scale = 0.f; ga.d[i].isV = 0;
    }
  }
  gemm_tiled<1><<<dim3(4, 32, 4), blk, 0, stream>>>(ga);

  FArgs fa;
  fa.tF[0] = tmpF_g; fa.tF[1] = tmpF_d;
  fa.tY[0] = tmpY_g; fa.tY[1] = tmpY_d;
  fa.emb[0] = gene; fa.emb[1] = drug;
  fa.gamma[0] = gg_g; fa.gamma[1] = dg_g;
  fa.beta[0] = gg_b; fa.beta[1] = dg_b;
  fa.out[0] = out; fa.out[1] = out + (size_t)SGQ * 512;
  ln_sig_combine_kernel<<<dim3(1024, 2), blk, 0, stream>>>(fa);
}

// Round 11
// 166.337 us; speedup vs baseline: 1.0878x; 1.0878x over previous
//
#include <hip/hip_runtime.h>
#include <hip/hip_bf16.h>

#define SGQ 4096
#define DMODEL 512
#define NH 8
#define DHEAD 64

typedef __attribute__((ext_vector_type(8))) short s16x8;
typedef __attribute__((ext_vector_type(4))) float f32x4;
typedef __attribute__((ext_vector_type(16))) float f32x16;
typedef __attribute__((ext_vector_type(4))) unsigned int u32x4;

__device__ inline ushort f2bf(float x) {
  unsigned u = __float_as_uint(x);
  return (ushort)((u + 0x7FFFu + ((u >> 16) & 1u)) >> 16);
}
__device__ inline float bf2f(ushort h) { return __uint_as_float(((unsigned)h) << 16); }
__device__ inline float exp2_hw(float x) {  // v_exp_f32 computes 2^x
  float r; asm("v_exp_f32 %0, %1" : "=v"(r) : "v"(x)); return r;
}
__device__ inline void gload16(const ushort* g, ushort* l) {
  __builtin_amdgcn_global_load_lds((const __attribute__((address_space(1))) void*)g,
                                   (__attribute__((address_space(3))) void*)l, 16, 0, 0);
}
// row->granule swizzle: each consecutive-8-lane group hits 8 distinct bank-quads
#define SWX(row) (((row) & 7) ^ (((row) >> 1) & 4))

// ================= merged prep: 9x weight convert/transpose + LayerNorm both sides ========
struct PArgs {
  const float* w[9]; ushort* wt[9]; int K[9];
  const float* x[2]; const float* gg[2]; const float* bb[2];
  ushort* normed[2]; ushort* cat[2];
};

__global__ __launch_bounds__(256) void prep_kernel(PArgs args) {
  int z = blockIdx.z;
  if (z < 9) {
    __shared__ float tile[32][33];
    int K = args.K[z];
    int k0 = blockIdx.y * 32;
    if (k0 >= K) return;
    const float* W = args.w[z];
    ushort* Wt = args.wt[z];
    int n0 = blockIdx.x * 32;
    int tx = threadIdx.x & 31, ty = threadIdx.x >> 5;
    #pragma unroll
    for (int i = ty; i < 32; i += 8) tile[i][tx] = W[(size_t)(k0 + i) * DMODEL + n0 + tx];
    __syncthreads();
    #pragma unroll
    for (int i = ty; i < 32; i += 8) Wt[(size_t)(n0 + i) * K + k0 + tx] = f2bf(tile[tx][i]);
  } else {
    int side = z - 9;
    int flat = blockIdx.x + (blockIdx.y << 4);   // [0,512)
    int lane = threadIdx.x & 63;
    const float* g = args.gg[side];
    const float* b = args.bb[side];
    #pragma unroll
    for (int pass = 0; pass < 2; ++pass) {
      int row = flat * 8 + pass * 4 + (threadIdx.x >> 6);
      const float* xr = args.x[side] + (size_t)row * DMODEL + lane * 8;
      float4 p0 = *(const float4*)xr;
      float4 p1 = *(const float4*)(xr + 4);
      float v[8] = {p0.x, p0.y, p0.z, p0.w, p1.x, p1.y, p1.z, p1.w};
      float s = 0.f;
      #pragma unroll
      for (int j = 0; j < 8; ++j) s += v[j];
      #pragma unroll
      for (int m = 1; m <= 32; m <<= 1) s += __shfl_xor(s, m);
      float mu = s * (1.0f / DMODEL);
      float q = 0.f;
      #pragma unroll
      for (int j = 0; j < 8; ++j) { float d = v[j] - mu; q += d * d; }
      #pragma unroll
      for (int m = 1; m <= 32; m <<= 1) q += __shfl_xor(q, m);
      float rs = rsqrtf(q * (1.0f / DMODEL) + 1e-5f);
      s16x8 nout, eout;
      #pragma unroll
      for (int j = 0; j < 8; ++j) {
        int c = lane * 8 + j;
        nout[j] = (short)f2bf((v[j] - mu) * rs * g[c] + b[c]);
        eout[j] = (short)f2bf(v[j]);
      }
      *(s16x8*)(args.normed[side] + (size_t)row * DMODEL + lane * 8) = nout;
      *(s16x8*)(args.cat[side] + (size_t)row * 1024 + DMODEL + lane * 8) = eout;
    }
  }
}

// ================= fused final: out = emb + sigmoid(LN(tmpF)) * tmpY (both sides) =========
struct FArgs {
  const float* tF[2]; const float* tY[2]; const float* emb[2];
  const float* gamma[2]; const float* beta[2]; float* out[2];
};

__global__ __launch_bounds__(256) void ln_sig_combine_kernel(FArgs args) {
  int side = blockIdx.y;
  int row = blockIdx.x * 4 + (threadIdx.x >> 6);
  int lane = threadIdx.x & 63;
  size_t base = (size_t)row * DMODEL + lane * 8;
  const float* xr = args.tF[side] + base;
  float4 p0 = *(const float4*)xr;
  float4 p1 = *(const float4*)(xr + 4);
  float v[8] = {p0.x, p0.y, p0.z, p0.w, p1.x, p1.y, p1.z, p1.w};
  float s = 0.f;
  #pragma unroll
  for (int j = 0; j < 8; ++j) s += v[j];
  #pragma unroll
  for (int m = 1; m <= 32; m <<= 1) s += __shfl_xor(s, m);
  float mu = s * (1.0f / DMODEL);
  float q = 0.f;
  #pragma unroll
  for (int j = 0; j < 8; ++j) { float d = v[j] - mu; q += d * d; }
  #pragma unroll
  for (int m = 1; m <= 32; m <<= 1) q += __shfl_xor(q, m);
  float rs = rsqrtf(q * (1.0f / DMODEL) + 1e-5f);
  const float* g = args.gamma[side];
  const float* b = args.beta[side];
  float4 y0 = *(const float4*)(args.tY[side] + base);
  float4 y1 = *(const float4*)(args.tY[side] + base + 4);
  float4 e0 = *(const float4*)(args.emb[side] + base);
  float4 e1 = *(const float4*)(args.emb[side] + base + 4);
  float yv[8] = {y0.x, y0.y, y0.z, y0.w, y1.x, y1.y, y1.z, y1.w};
  float ev[8] = {e0.x, e0.y, e0.z, e0.w, e1.x, e1.y, e1.z, e1.w};
  float ov[8];
  #pragma unroll
  for (int j = 0; j < 8; ++j) {
    int c = lane * 8 + j;
    float y = (v[j] - mu) * rs * g[c] + b[c];
    float gate = 1.0f / (1.0f + __expf(-y));
    ov[j] = ev[j] + gate * yv[j];
  }
  float4 o0 = {ov[0], ov[1], ov[2], ov[3]};
  float4 o1 = {ov[4], ov[5], ov[6], ov[7]};
  *(float4*)(args.out[side] + base) = o0;
  *(float4*)(args.out[side] + base + 4) = o1;
}

// ================= unified 128x128-tile GEMM, global_load_lds staging (m97 structure) =====
struct GemmDesc {
  const ushort* A; const ushort* Wt; const float* bias;
  void* dst; const float* emb; const ushort* gate;
  int lda; int K; float scale; int isV;
};
struct GemmArgs { GemmDesc d[6]; };

template <int EPI>
__global__ __launch_bounds__(256, 2) void gemm_tiled(GemmArgs args) {
  __shared__ __align__(16) ushort Ash[2][128 * 32];
  __shared__ __align__(16) ushort Bsh[2][128 * 32];
  const GemmDesc& D = args.d[blockIdx.z];
  const int tid = threadIdx.x;
  const int w = tid >> 6, lane = tid & 63;
  const int ln = lane & 15, g = lane >> 4;
  const int wr = w >> 1, wc = w & 1;
  const int rowT = blockIdx.y * 128, colT = blockIdx.x * 128;
  const int K = D.K, lda = D.lda;
  const int srow = lane >> 2, scol = (lane & 3) * 8;

  f32x4 zero = {0.f, 0.f, 0.f, 0.f};
  f32x4 acc[4][4];
  #pragma unroll
  for (int m = 0; m < 4; ++m)
    #pragma unroll
    for (int n = 0; n < 4; ++n) acc[m][n] = zero;

  auto stage = [&](int cur, int k0) {
    #pragma unroll
    for (int c = 0; c < 2; ++c) {
      const int rbase = c * 64 + w * 16;
      gload16(D.A + (size_t)(rowT + rbase + srow) * lda + k0 + scol, &Ash[cur][rbase * 32]);
      gload16(D.Wt + (size_t)(colT + rbase + srow) * K + k0 + scol, &Bsh[cur][rbase * 32]);
    }
  };

  stage(0, 0);
  const int nT = K >> 5;
  for (int t = 0; t < nT; ++t) {
    const int cur = t & 1;
    __syncthreads();
    if (t + 1 < nT) stage(cur ^ 1, (t + 1) * 32);
    s16x8 af[4], bf[4];
    #pragma unroll
    for (int m = 0; m < 4; ++m) {
      af[m] = *(const s16x8*)&Ash[cur][(wr * 64 + m * 16 + ln) * 32 + g * 8];
      bf[m] = *(const s16x8*)&Bsh[cur][(wc * 64 + m * 16 + ln) * 32 + g * 8];
    }
    #pragma unroll
    for (int m = 0; m < 4; ++m)
      #pragma unroll
      for (int n = 0; n < 4; ++n)
        acc[m][n] = __builtin_amdgcn_mfma_f32_16x16x32_bf16(af[m], bf[n], acc[m][n], 0, 0, 0);
  }

  const float* bias = D.bias;
  const int colw = colT + wc * 64;
  if (EPI == 0) {
    const int h = colw >> 6;
    if (!D.isV) {
      float sc[4][4];
      #pragma unroll
      for (int m = 0; m < 4; ++m) {
        float ss[4] = {0.f, 0.f, 0.f, 0.f};
        #pragma unroll
        for (int n = 0; n < 4; ++n) {
          float bv = bias[colw + n * 16 + ln];
          #pragma unroll
          for (int r = 0; r < 4; ++r) {
            float v = acc[m][n][r] + bv;
            acc[m][n][r] = v;
            ss[r] += v * v;
          }
        }
        #pragma unroll
        for (int r = 0; r < 4; ++r) {
          float v = ss[r];
          v += __shfl_xor(v, 1); v += __shfl_xor(v, 2);
          v += __shfl_xor(v, 4); v += __shfl_xor(v, 8);
          sc[m][r] = D.scale / fmaxf(sqrtf(v), 1e-12f);
        }
      }
      ushort* dst = (ushort*)D.dst;
      #pragma unroll
      for (int m = 0; m < 4; ++m)
        #pragma unroll
        for (int n = 0; n < 4; ++n)
          #pragma unroll
          for (int r = 0; r < 4; ++r) {
            int row = rowT + wr * 64 + m * 16 + g * 4 + r;
            dst[((size_t)h * SGQ + row) * DHEAD + n * 16 + ln] = f2bf(acc[m][n][r] * sc[m][r]);
          }
    } else {
      ushort* dst = (ushort*)D.dst;
      #pragma unroll
      for (int m = 0; m < 4; ++m)
        #pragma unroll
        for (int n = 0; n < 4; ++n) {
          int d = n * 16 + ln;
          float bv = bias[colw + d];
          uint lo = (uint)f2bf(acc[m][n][0] + bv) | ((uint)f2bf(acc[m][n][1] + bv) << 16);
          uint hi2 = (uint)f2bf(acc[m][n][2] + bv) | ((uint)f2bf(acc[m][n][3] + bv) << 16);
          int s0 = rowT + wr * 64 + m * 16 + g * 4;
          uint2 pk; pk.x = lo; pk.y = hi2;
          *(uint2*)(dst + (size_t)(h * DHEAD + d) * SGQ + s0) = pk;
        }
    }
  } else {
    float* outF = (float*)D.dst;
    #pragma unroll
    for (int m = 0; m < 4; ++m)
      #pragma unroll
      for (int n = 0; n < 4; ++n) {
        float bv = bias[colw + n * 16 + ln];
        #pragma unroll
        for (int r = 0; r < 4; ++r)
          outF[(size_t)(rowT + wr * 64 + m * 16 + g * 4 + r) * DMODEL + colw + n * 16 + ln] =
              acc[m][n][r] + bv;
      }
  }
}

// ================= attention: 64 q/wave, in-kernel key-split, 4-wave blocks ===============
// qn[s]: [H][Sq][64] (l2*0.125*log2e), kn: [H][Sk][64], vt: [H][64][Sk].
// Wave (wq = w&1, kh = w>>1): q-rows [qb*128 + wq*64, +64), keys [kh*2048, +2048).
// Each 2-wave pair (same kh) has its own double-buffered 64-key K/V tile; every ka/vb
// LDS read feeds 2 MFMAs (two 32-q groups) -> LDS read bytes per FLOP halved vs R9.
// S^T = mfma(A=K_perm, B=Q); bit2<->3-swapped A rows make each lane's 16 C regs
// consecutive-k; cvt_pk pairs feed PV's A-fragment directly.
// Key-half partials combine through LDS at the end (exact: softmax has no running max).
struct AArgs { const ushort* qn[2]; const ushort* kn[2]; const ushort* vt[2]; ushort* cat[2]; };

__global__ __launch_bounds__(256, 2) void attn_kernel(AArgs args) {
  __shared__ __align__(16) ushort Ksh[2][2][64 * 64];   // [kh][buf]
  __shared__ __align__(16) ushort Vsh[2][2][64 * 64];
  const int side = blockIdx.z, h = blockIdx.y, qb = blockIdx.x;
  const int w = threadIdx.x >> 6, lane = threadIdx.x & 63;
  const int wq = w & 1, kh = w >> 1;
  const int kbase = kh * (SGQ / 2);
  const int l32 = lane & 31, hi = lane >> 5;
  const int l8 = lane & 7, lr = lane >> 3;
  const ushort* qnh = args.qn[side] + (size_t)h * SGQ * DHEAD;
  const ushort* knh = args.kn[side] + (size_t)h * SGQ * DHEAD;
  const ushort* vth = args.vt[side] + (size_t)h * DHEAD * SGQ;
  ushort* cat = args.cat[side];
  const int r0w = qb * 128 + wq * 64;   // this wave's 64 q rows

  s16x8 qf[2][4];
  #pragma unroll
  for (int qg = 0; qg < 2; ++qg)
    #pragma unroll
    for (int s = 0; s < 4; ++s)
      qf[qg][s] = *(const s16x8*)(qnh + (size_t)(r0w + qg * 32 + l32) * DHEAD + s * 16 + hi * 8);

  // within its pair, wave wq stages K rows [wq*32,+32) and V d-rows [wq*32,+32)
  s16x8 sk[4], sv[4];
  auto prefetch = [&](int key0) {
    #pragma unroll
    for (int c = 0; c < 4; ++c) {
      int row = wq * 32 + c * 8 + lr;
      sk[c] = *(const s16x8*)(knh + (size_t)(key0 + row) * DHEAD + l8 * 8);
      sv[c] = *(const s16x8*)(vth + (size_t)row * SGQ + key0 + l8 * 8);
    }
  };

  const f32x16 Z = {0,0,0,0,0,0,0,0,0,0,0,0,0,0,0,0};
  f32x16 o[2][2];   // [qg][d-half]
  o[0][0] = Z; o[0][1] = Z; o[1][0] = Z; o[1][1] = Z;
  float rsA[2] = {0.f, 0.f}, rsB[2] = {0.f, 0.f};
  const int krp = (l32 & 19) | ((l32 & 4) << 1) | ((l32 & 8) >> 1);  // swap bits 2<->3

  prefetch(kbase);
  for (int t = 0; t < 32; ++t) {
    const int cur = t & 1;
    #pragma unroll
    for (int c = 0; c < 4; ++c) {
      int row = wq * 32 + c * 8 + lr;
      int colsw = (l8 ^ SWX(row)) * 8;
      *(s16x8*)&Ksh[kh][cur][row * 64 + colsw] = sk[c];
      *(s16x8*)&Vsh[kh][cur][row * 64 + colsw] = sv[c];
    }
    asm volatile("s_waitcnt lgkmcnt(0)" ::: "memory");
    __builtin_amdgcn_s_barrier();
    asm volatile("" ::: "memory");
    if (t < 31) prefetch(kbase + ((t + 1) << 6));
    #pragma unroll
    for (int st = 0; st < 2; ++st) {
      const int kr = st * 32 + krp;
      const int rsw = SWX(kr);
      s16x8 ka[4];
      #pragma unroll
      for (int s = 0; s < 4; ++s)
        ka[s] = *(const s16x8*)&Ksh[kh][cur][kr * 64 + (((s * 2 + hi) ^ rsw) * 8)];
      f32x16 S0 = Z, S1 = Z;
      __builtin_amdgcn_s_setprio(1);
      #pragma unroll
      for (int s = 0; s < 4; ++s) {
        S0 = __builtin_amdgcn_mfma_f32_32x32x16_bf16(ka[s], qf[0][s], S0, 0, 0, 0);
        S1 = __builtin_amdgcn_mfma_f32_32x32x16_bf16(ka[s], qf[1][s], S1, 0, 0, 0);
      }
      __builtin_amdgcn_s_setprio(0);
      // clip(-10,10) is a provable no-op; scores pre-scaled by log2e -> exp2 directly
      #pragma unroll
      for (int i = 0; i < 16; ++i) S0[i] = exp2_hw(S0[i]);
      #pragma unroll
      for (int i = 0; i < 16; ++i) S1[i] = exp2_hw(S1[i]);
      #pragma unroll
      for (int i = 0; i < 16; i += 2) {
        rsA[0] += S0[i]; rsB[0] += S0[i + 1];
        rsA[1] += S1[i]; rsB[1] += S1[i + 1];
      }
      uint u0[8], u1[8];
      #pragma unroll
      for (int j2 = 0; j2 < 8; ++j2) {
        uint r_;
        asm("v_cvt_pk_bf16_f32 %0, %1, %2" : "=v"(r_) : "v"(S0[2 * j2]), "v"(S0[2 * j2 + 1]));
        u0[j2] = r_;
        asm("v_cvt_pk_bf16_f32 %0, %1, %2" : "=v"(r_) : "v"(S1[2 * j2]), "v"(S1[2 * j2 + 1]));
        u1[j2] = r_;
      }
      __builtin_amdgcn_s_setprio(1);
      #pragma unroll
      for (int slot = 0; slot < 2; ++slot) {
        u32x4 uv0 = {u0[slot * 4 + 0], u0[slot * 4 + 1], u0[slot * 4 + 2], u0[slot * 4 + 3]};
        u32x4 uv1 = {u1[slot * 4 + 0], u1[slot * 4 + 1], u1[slot * 4 + 2], u1[slot * 4 + 3]};
        s16x8 pf0 = __builtin_bit_cast(s16x8, uv0);
        s16x8 pf1 = __builtin_bit_cast(s16x8, uv1);
        const int kcg = st * 4 + slot * 2 + hi;   // key-col granule
        #pragma unroll
        for (int dh = 0; dh < 2; ++dh) {
          const int vr = dh * 32 + l32;
          s16x8 vb = *(const s16x8*)&Vsh[kh][cur][vr * 64 + ((kcg ^ SWX(vr)) * 8)];
          o[0][dh] = __builtin_amdgcn_mfma_f32_32x32x16_bf16(pf0, vb, o[0][dh], 0, 0, 0);
          o[1][dh] = __builtin_amdgcn_mfma_f32_32x32x16_bf16(pf1, vb, o[1][dh], 0, 0, 0);
        }
      }
      __builtin_amdgcn_s_setprio(0);
    }
  }

  // ---- combine key-halves (kh=1 -> LDS -> kh=0), normalize, write cat ----
  float rsum[2];
  #pragma unroll
  for (int qg = 0; qg < 2; ++qg) {
    float v = rsA[qg] + rsB[qg];
    v += __shfl_xor(v, 32);
    rsum[qg] = v;
  }
  __syncthreads();                      // all tile reads done; LDS reusable
  float* LF = (float*)&Ksh[0][0][0];    // 8192 floats (o partials)
  float* LR = LF + 2 * 64 * 64;         // rsum partials (in dead Vsh space)
  const int lb = (wq * 64 + lane) * 64;
  if (kh == 1) {
    *(f32x16*)&LF[lb + 0]  = o[0][0];
    *(f32x16*)&LF[lb + 16] = o[0][1];
    *(f32x16*)&LF[lb + 32] = o[1][0];
    *(f32x16*)&LF[lb + 48] = o[1][1];
    LR[(wq * 64 + lane) * 2 + 0] = rsum[0];
    LR[(wq * 64 + lane) * 2 + 1] = rsum[1];
  }
  __syncthreads();
  if (kh == 0) {
    f32x16 p00 = *(const f32x16*)&LF[lb + 0];
    f32x16 p01 = *(const f32x16*)&LF[lb + 16];
    f32x16 p10 = *(const f32x16*)&LF[lb + 32];
    f32x16 p11 = *(const f32x16*)&LF[lb + 48];
    o[0][0] += p00; o[0][1] += p01; o[1][0] += p10; o[1][1] += p11;
    float inv0 = 1.0f / (rsum[0] + LR[(wq * 64 + lane) * 2 + 0]);
    float inv1 = 1.0f / (rsum[1] + LR[(wq * 64 + lane) * 2 + 1]);
    #pragma unroll
    for (int r = 0; r < 16; ++r) {
      const int qr = (r & 3) + 8 * (r >> 2) + 4 * hi;
      float iv0 = __shfl(inv0, qr);
      float iv1 = __shfl(inv1, qr);
      size_t b0 = (size_t)(r0w + qr) * 1024 + h * DHEAD + l32;
      cat[b0] = f2bf(o[0][0][r] * iv0);
      cat[b0 + 32] = f2bf(o[0][1][r] * iv0);
      size_t b1 = (size_t)(r0w + 32 + qr) * 1024 + h * DHEAD + l32;
      cat[b1] = f2bf(o[1][0][r] * iv1);
      cat[b1 + 32] = f2bf(o[1][1][r] * iv1);
    }
  }
}

// ================= host ====================================================================
extern "C" void kernel_launch(void* const* d_in, const int* in_sizes, int n_in,
                              void* d_out, int out_size, void* d_ws, size_t ws_size,
                              hipStream_t stream) {
  const float* gene = (const float*)d_in[0];
  const float* drug = (const float*)d_in[1];
  const float* lng_g = (const float*)d_in[2];
  const float* lng_b = (const float*)d_in[3];
  const float* lnd_g = (const float*)d_in[4];
  const float* lnd_b = (const float*)d_in[5];
  const float* wgq = (const float*)d_in[6];  const float* bgq = (const float*)d_in[7];
  const float* wgk = (const float*)d_in[8];  const float* bgk = (const float*)d_in[9];
  const float* wgv = (const float*)d_in[10]; const float* bgv = (const float*)d_in[11];
  const float* wdq = (const float*)d_in[12]; const float* bdq = (const float*)d_in[13];
  const float* wdk = (const float*)d_in[14]; const float* bdk = (const float*)d_in[15];
  const float* wdv = (const float*)d_in[16]; const float* bdv = (const float*)d_in[17];
  const float* wo  = (const float*)d_in[18]; const float* bo  = (const float*)d_in[19];
  const float* wgg = (const float*)d_in[20]; const float* bgg = (const float*)d_in[21];
  const float* gg_g = (const float*)d_in[22]; const float* gg_b = (const float*)d_in[23];
  const float* wdg = (const float*)d_in[24]; const float* bdg = (const float*)d_in[25];
  const float* dg_g = (const float*)d_in[26]; const float* dg_b = (const float*)d_in[27];
  float* out = (float*)d_out;

  char* p = (char*)d_ws;
  size_t off = 0;
  auto alloc = [&](size_t bytes) { char* r = p + off; off = (off + bytes + 255) & ~(size_t)255; return r; };
  ushort* wT_gq = (ushort*)alloc(512 * 512 * 2);
  ushort* wT_gk = (ushort*)alloc(512 * 512 * 2);
  ushort* wT_gv = (ushort*)alloc(512 * 512 * 2);
  ushort* wT_dq = (ushort*)alloc(512 * 512 * 2);
  ushort* wT_dk = (ushort*)alloc(512 * 512 * 2);
  ushort* wT_dv = (ushort*)alloc(512 * 512 * 2);
  ushort* wT_o  = (ushort*)alloc(512 * 512 * 2);
  ushort* wT_gg = (ushort*)alloc(1024 * 512 * 2);
  ushort* wT_dg = (ushort*)alloc(1024 * 512 * 2);
  ushort* ng   = (ushort*)alloc((size_t)SGQ * 512 * 2);   // + nd = contiguous 8 MB
  ushort* nd   = (ushort*)alloc((size_t)SGQ * 512 * 2);
  ushort* catg = (ushort*)alloc((size_t)SGQ * 1024 * 2);
  ushort* catd = (ushort*)alloc((size_t)SGQ * 1024 * 2);
  ushort* qn_g = (ushort*)alloc((size_t)SGQ * 512 * 2);   // + kn_g = contiguous 8 MB
  ushort* kn_g = (ushort*)alloc((size_t)SGQ * 512 * 2);
  ushort* qn_d = (ushort*)alloc((size_t)SGQ * 512 * 2);   // + kn_d = contiguous 8 MB
  ushort* kn_d = (ushort*)alloc((size_t)SGQ * 512 * 2);
  ushort* vt_g = (ushort*)alloc((size_t)SGQ * 512 * 2);   // + vt_d = contiguous 8 MB
  ushort* vt_d = (ushort*)alloc((size_t)SGQ * 512 * 2);
  // dead-buffer reuse after attention (qn/kn/vt dead) and after qkv (ng/nd dead):
  float* tmpF_g = (float*)qn_g;   // 8 MB f32 spans qn_g+kn_g
  float* tmpF_d = (float*)qn_d;   // 8 MB f32 spans qn_d+kn_d
  float* tmpY_g = (float*)vt_g;   // 8 MB f32 spans vt_g+vt_d
  float* tmpY_d = (float*)ng;     // 8 MB f32 spans ng+nd

  dim3 blk(256);
  const float QSCALE = 0.125f * 1.4426950408889634f;  // head-scale * log2(e)

  PArgs pa;
  {
    const float* ws_[9] = {wgq, wgk, wgv, wdq, wdk, wdv, wo, wgg, wdg};
    ushort* wt_[9] = {wT_gq, wT_gk, wT_gv, wT_dq, wT_dk, wT_dv, wT_o, wT_gg, wT_dg};
    int k_[9] = {512, 512, 512, 512, 512, 512, 512, 1024, 1024};
    for (int i = 0; i < 9; ++i) { pa.w[i] = ws_[i]; pa.wt[i] = wt_[i]; pa.K[i] = k_[i]; }
    pa.x[0] = gene; pa.x[1] = drug;
    pa.gg[0] = lng_g; pa.gg[1] = lnd_g;
    pa.bb[0] = lng_b; pa.bb[1] = lnd_b;
    pa.normed[0] = ng; pa.normed[1] = nd;
    pa.cat[0] = catg; pa.cat[1] = catd;
  }
  prep_kernel<<<dim3(16, 32, 11), blk, 0, stream>>>(pa);

  GemmArgs qa;
  {
    const ushort* A_[6] = {ng, ng, catg + 512, nd, nd, catd + 512};
    const ushort* W_[6] = {wT_gq, wT_gk, wT_gv, wT_dq, wT_dk, wT_dv};
    const float* B_[6] = {bgq, bgk, bgv, bdq, bdk, bdv};
    ushort* D_[6] = {qn_g, kn_g, vt_g, qn_d, kn_d, vt_d};
    int lda_[6] = {512, 512, 1024, 512, 512, 1024};
    float sc_[6] = {QSCALE, 1.0f, 0.f, QSCALE, 1.0f, 0.f};
    int iv_[6] = {0, 0, 1, 0, 0, 1};
    for (int i = 0; i < 6; ++i) {
      qa.d[i].A = A_[i]; qa.d[i].Wt = W_[i]; qa.d[i].bias = B_[i];
      qa.d[i].dst = D_[i]; qa.d[i].emb = nullptr; qa.d[i].gate = nullptr;
      qa.d[i].lda = lda_[i]; qa.d[i].K = 512; qa.d[i].scale = sc_[i]; qa.d[i].isV = iv_[i];
    }
  }
  gemm_tiled<0><<<dim3(4, 32, 6), blk, 0, stream>>>(qa);

  AArgs aa;
  aa.qn[0] = qn_g; aa.qn[1] = qn_d;
  aa.kn[0] = kn_d; aa.kn[1] = kn_g;   // cross: gene-q attends drug-K/V, and vice versa
  aa.vt[0] = vt_d; aa.vt[1] = vt_g;
  aa.cat[0] = catg; aa.cat[1] = catd;
  attn_kernel<<<dim3(32, 8, 2), blk, 0, stream>>>(aa);

  // gate pre-LN GEMM (z=0,1) and ctx@wo+bo (z=2,3) in ONE dispatch
  GemmArgs ga;
  {
    const ushort* A_[4] = {catg, catd, catg, catd};
    const ushort* W_[4] = {wT_gg, wT_dg, wT_o, wT_o};
    const float* B_[4] = {bgg, bdg, bo, bo};
    float* D_[4] = {tmpF_g, tmpF_d, tmpY_g, tmpY_d};
    int k_[4] = {1024, 1024, 512, 512};
    for (int i = 0; i < 4; ++i) {
      ga.d[i].A = A_[i]; ga.d[i].Wt = W_[i]; ga.d[i].bias = B_[i];
      ga.d[i].dst = D_[i]; ga.d[i].emb = nullptr; ga.d[i].gate = nullptr;
      ga.d[i].lda = 1024; ga.d[i].K = k_[i]; ga.d[i].scale = 0.f; ga.d[i].isV = 0;
    }
  }
  gemm_tiled<1><<<dim3(4, 32, 4), blk, 0, stream>>>(ga);

  FArgs fa;
  fa.tF[0] = tmpF_g; fa.tF[1] = tmpF_d;
  fa.tY[0] = tmpY_g; fa.tY[1] = tmpY_d;
  fa.emb[0] = gene; fa.emb[1] = drug;
  fa.gamma[0] = gg_g; fa.gamma[1] = dg_g;
  fa.beta[0] = gg_b; fa.beta[1] = dg_b;
  fa.out[0] = out; fa.out[1] = out + (size_t)SGQ * 512;
  ln_sig_combine_kernel<<<dim3(1024, 2), blk, 0, stream>>>(fa);
}

// Round 12
// 158.123 us; speedup vs baseline: 1.1443x; 1.0519x over previous
//
#include <hip/hip_runtime.h>
#include <hip/hip_bf16.h>

#define SGQ 4096
#define DMODEL 512
#define NH 8
#define DHEAD 64

typedef __attribute__((ext_vector_type(8))) short s16x8;
typedef __attribute__((ext_vector_type(4))) float f32x4;
typedef __attribute__((ext_vector_type(16))) float f32x16;
typedef __attribute__((ext_vector_type(4))) unsigned int u32x4;

__device__ inline ushort f2bf(float x) {
  unsigned u = __float_as_uint(x);
  return (ushort)((u + 0x7FFFu + ((u >> 16) & 1u)) >> 16);
}
__device__ inline float bf2f(ushort h) { return __uint_as_float(((unsigned)h) << 16); }
__device__ inline float exp2_hw(float x) {  // v_exp_f32 computes 2^x
  float r; asm("v_exp_f32 %0, %1" : "=v"(r) : "v"(x)); return r;
}
__device__ inline void gload16(const ushort* g, ushort* l) {
  __builtin_amdgcn_global_load_lds((const __attribute__((address_space(1))) void*)g,
                                   (__attribute__((address_space(3))) void*)l, 16, 0, 0);
}
// row->granule swizzles: each consecutive-8-lane group hits 8 distinct bank-quads
#define SWX(row) (((row) & 7) ^ (((row) >> 1) & 4))
#define S16(row) ((row) & 15)

// ================= merged prep: 9x weight convert/transpose + LayerNorm both sides ========
struct PArgs {
  const float* w[9]; ushort* wt[9]; int K[9];
  const float* x[2]; const float* gg[2]; const float* bb[2];
  ushort* normed[2]; ushort* cat[2];
};

__global__ __launch_bounds__(256) void prep_kernel(PArgs args) {
  int z = blockIdx.z;
  if (z < 9) {
    __shared__ float tile[32][33];
    int K = args.K[z];
    int k0 = blockIdx.y * 32;
    if (k0 >= K) return;
    const float* W = args.w[z];
    ushort* Wt = args.wt[z];
    int n0 = blockIdx.x * 32;
    int tx = threadIdx.x & 31, ty = threadIdx.x >> 5;
    #pragma unroll
    for (int i = ty; i < 32; i += 8) tile[i][tx] = W[(size_t)(k0 + i) * DMODEL + n0 + tx];
    __syncthreads();
    #pragma unroll
    for (int i = ty; i < 32; i += 8) Wt[(size_t)(n0 + i) * K + k0 + tx] = f2bf(tile[tx][i]);
  } else {
    int side = z - 9;
    int flat = blockIdx.x + (blockIdx.y << 4);   // [0,512)
    int lane = threadIdx.x & 63;
    const float* g = args.gg[side];
    const float* b = args.bb[side];
    #pragma unroll
    for (int pass = 0; pass < 2; ++pass) {
      int row = flat * 8 + pass * 4 + (threadIdx.x >> 6);
      const float* xr = args.x[side] + (size_t)row * DMODEL + lane * 8;
      float4 p0 = *(const float4*)xr;
      float4 p1 = *(const float4*)(xr + 4);
      float v[8] = {p0.x, p0.y, p0.z, p0.w, p1.x, p1.y, p1.z, p1.w};
      float s = 0.f;
      #pragma unroll
      for (int j = 0; j < 8; ++j) s += v[j];
      #pragma unroll
      for (int m = 1; m <= 32; m <<= 1) s += __shfl_xor(s, m);
      float mu = s * (1.0f / DMODEL);
      float q = 0.f;
      #pragma unroll
      for (int j = 0; j < 8; ++j) { float d = v[j] - mu; q += d * d; }
      #pragma unroll
      for (int m = 1; m <= 32; m <<= 1) q += __shfl_xor(q, m);
      float rs = rsqrtf(q * (1.0f / DMODEL) + 1e-5f);
      s16x8 nout, eout;
      #pragma unroll
      for (int j = 0; j < 8; ++j) {
        int c = lane * 8 + j;
        nout[j] = (short)f2bf((v[j] - mu) * rs * g[c] + b[c]);
        eout[j] = (short)f2bf(v[j]);
      }
      *(s16x8*)(args.normed[side] + (size_t)row * DMODEL + lane * 8) = nout;
      *(s16x8*)(args.cat[side] + (size_t)row * 1024 + DMODEL + lane * 8) = eout;
    }
  }
}

// ================= fused final: out = emb + sigmoid(LN(tmpF)) * tmpY (bf16 inputs) ========
struct FArgs {
  const ushort* tF[2]; const ushort* tY[2]; const float* emb[2];
  const float* gamma[2]; const float* beta[2]; float* out[2];
};

__global__ __launch_bounds__(256) void ln_sig_combine_kernel(FArgs args) {
  int side = blockIdx.y;
  int row = blockIdx.x * 4 + (threadIdx.x >> 6);
  int lane = threadIdx.x & 63;
  size_t base = (size_t)row * DMODEL + lane * 8;
  s16x8 xv = *(const s16x8*)(args.tF[side] + base);
  float v[8];
  #pragma unroll
  for (int j = 0; j < 8; ++j) v[j] = bf2f((ushort)xv[j]);
  float s = 0.f;
  #pragma unroll
  for (int j = 0; j < 8; ++j) s += v[j];
  #pragma unroll
  for (int m = 1; m <= 32; m <<= 1) s += __shfl_xor(s, m);
  float mu = s * (1.0f / DMODEL);
  float q = 0.f;
  #pragma unroll
  for (int j = 0; j < 8; ++j) { float d = v[j] - mu; q += d * d; }
  #pragma unroll
  for (int m = 1; m <= 32; m <<= 1) q += __shfl_xor(q, m);
  float rs = rsqrtf(q * (1.0f / DMODEL) + 1e-5f);
  const float* g = args.gamma[side];
  const float* b = args.beta[side];
  s16x8 yv16 = *(const s16x8*)(args.tY[side] + base);
  float4 e0 = *(const float4*)(args.emb[side] + base);
  float4 e1 = *(const float4*)(args.emb[side] + base + 4);
  float ev[8] = {e0.x, e0.y, e0.z, e0.w, e1.x, e1.y, e1.z, e1.w};
  float ov[8];
  #pragma unroll
  for (int j = 0; j < 8; ++j) {
    int c = lane * 8 + j;
    float y = (v[j] - mu) * rs * g[c] + b[c];
    float gate = 1.0f / (1.0f + __expf(-y));
    ov[j] = ev[j] + gate * bf2f((ushort)yv16[j]);
  }
  float4 o0 = {ov[0], ov[1], ov[2], ov[3]};
  float4 o1 = {ov[4], ov[5], ov[6], ov[7]};
  *(float4*)(args.out[side] + base) = o0;
  *(float4*)(args.out[side] + base + 4) = o1;
}

// ================= unified 128x128-tile GEMM, global_load_lds staging (m97 structure) =====
struct GemmDesc {
  const ushort* A; const ushort* Wt; const float* bias;
  void* dst; const float* emb; const ushort* gate;
  int lda; int K; float scale; int isV;
};
struct GemmArgs { GemmDesc d[6]; };

// EPI 0: qkv (isV? transposed-V write : per-head l2norm+scale write).  EPI 1: bf16 out.
template <int EPI>
__global__ __launch_bounds__(256, 2) void gemm_tiled(GemmArgs args) {
  __shared__ __align__(16) ushort Ash[2][128 * 32];
  __shared__ __align__(16) ushort Bsh[2][128 * 32];
  const GemmDesc& D = args.d[blockIdx.z];
  const int tid = threadIdx.x;
  const int w = tid >> 6, lane = tid & 63;
  const int ln = lane & 15, g = lane >> 4;
  const int wr = w >> 1, wc = w & 1;
  const int rowT = blockIdx.y * 128, colT = blockIdx.x * 128;
  const int K = D.K, lda = D.lda;
  const int srow = lane >> 2, scol = (lane & 3) * 8;

  f32x4 zero = {0.f, 0.f, 0.f, 0.f};
  f32x4 acc[4][4];
  #pragma unroll
  for (int m = 0; m < 4; ++m)
    #pragma unroll
    for (int n = 0; n < 4; ++n) acc[m][n] = zero;

  auto stage = [&](int cur, int k0) {
    #pragma unroll
    for (int c = 0; c < 2; ++c) {
      const int rbase = c * 64 + w * 16;
      gload16(D.A + (size_t)(rowT + rbase + srow) * lda + k0 + scol, &Ash[cur][rbase * 32]);
      gload16(D.Wt + (size_t)(colT + rbase + srow) * K + k0 + scol, &Bsh[cur][rbase * 32]);
    }
  };

  stage(0, 0);
  const int nT = K >> 5;
  for (int t = 0; t < nT; ++t) {
    const int cur = t & 1;
    __syncthreads();
    if (t + 1 < nT) stage(cur ^ 1, (t + 1) * 32);
    s16x8 af[4], bf[4];
    #pragma unroll
    for (int m = 0; m < 4; ++m) {
      af[m] = *(const s16x8*)&Ash[cur][(wr * 64 + m * 16 + ln) * 32 + g * 8];
      bf[m] = *(const s16x8*)&Bsh[cur][(wc * 64 + m * 16 + ln) * 32 + g * 8];
    }
    #pragma unroll
    for (int m = 0; m < 4; ++m)
      #pragma unroll
      for (int n = 0; n < 4; ++n)
        acc[m][n] = __builtin_amdgcn_mfma_f32_16x16x32_bf16(af[m], bf[n], acc[m][n], 0, 0, 0);
  }

  const float* bias = D.bias;
  const int colw = colT + wc * 64;
  if (EPI == 0) {
    const int h = colw >> 6;
    if (!D.isV) {
      float sc[4][4];
      #pragma unroll
      for (int m = 0; m < 4; ++m) {
        float ss[4] = {0.f, 0.f, 0.f, 0.f};
        #pragma unroll
        for (int n = 0; n < 4; ++n) {
          float bv = bias[colw + n * 16 + ln];
          #pragma unroll
          for (int r = 0; r < 4; ++r) {
            float v = acc[m][n][r] + bv;
            acc[m][n][r] = v;
            ss[r] += v * v;
          }
        }
        #pragma unroll
        for (int r = 0; r < 4; ++r) {
          float v = ss[r];
          v += __shfl_xor(v, 1); v += __shfl_xor(v, 2);
          v += __shfl_xor(v, 4); v += __shfl_xor(v, 8);
          sc[m][r] = D.scale / fmaxf(sqrtf(v), 1e-12f);
        }
      }
      ushort* dst = (ushort*)D.dst;
      #pragma unroll
      for (int m = 0; m < 4; ++m)
        #pragma unroll
        for (int n = 0; n < 4; ++n)
          #pragma unroll
          for (int r = 0; r < 4; ++r) {
            int row = rowT + wr * 64 + m * 16 + g * 4 + r;
            dst[((size_t)h * SGQ + row) * DHEAD + n * 16 + ln] = f2bf(acc[m][n][r] * sc[m][r]);
          }
    } else {
      ushort* dst = (ushort*)D.dst;
      #pragma unroll
      for (int m = 0; m < 4; ++m)
        #pragma unroll
        for (int n = 0; n < 4; ++n) {
          int d = n * 16 + ln;
          float bv = bias[colw + d];
          uint lo = (uint)f2bf(acc[m][n][0] + bv) | ((uint)f2bf(acc[m][n][1] + bv) << 16);
          uint hi2 = (uint)f2bf(acc[m][n][2] + bv) | ((uint)f2bf(acc[m][n][3] + bv) << 16);
          int s0 = rowT + wr * 64 + m * 16 + g * 4;
          uint2 pk; pk.x = lo; pk.y = hi2;
          *(uint2*)(dst + (size_t)(h * DHEAD + d) * SGQ + s0) = pk;
        }
    }
  } else {
    ushort* outB = (ushort*)D.dst;
    #pragma unroll
    for (int m = 0; m < 4; ++m)
      #pragma unroll
      for (int n = 0; n < 4; ++n) {
        float bv = bias[colw + n * 16 + ln];
        #pragma unroll
        for (int r = 0; r < 4; ++r)
          outB[(size_t)(rowT + wr * 64 + m * 16 + g * 4 + r) * DMODEL + colw + n * 16 + ln] =
              f2bf(acc[m][n][r] + bv);
      }
  }
}

// ================= attention (R9-verified): KVBLK=128, MFMA rowsum =======================
// qn[s]: [H][Sq][64] (l2*0.125*log2e), kn: [H][Sk][64], vt: [H][64][Sk].
// S^T = mfma(A=K_perm, B=Q); bit2<->3-swapped A rows make each lane's 16 C regs
// consecutive-k; cvt_pk pairs feed PV's A-fragment directly.
// Rowsum computed on the MFMA pipe: osum = mfma(pf, ONES, osum) -> C[q][*] = sum_k P[q][k],
// replicated over lanes, reg-mapping identical to o0/o1 (same A operand) -> no epilogue shfl.
struct AArgs { const ushort* qn[2]; const ushort* kn[2]; const ushort* vt[2]; ushort* cat[2]; };

__global__ __launch_bounds__(256, 2) void attn_kernel(AArgs args) {
  __shared__ __align__(16) ushort Ksh[2][128 * 64];
  __shared__ __align__(16) ushort Vsh[2][64 * 128];
  const int side = blockIdx.z, h = blockIdx.y, qb = blockIdx.x;
  const int w = threadIdx.x >> 6, lane = threadIdx.x & 63;
  const int l32 = lane & 31, hi = lane >> 5;
  const int l8 = lane & 7, lr = lane >> 3;
  const ushort* qnh = args.qn[side] + (size_t)h * SGQ * DHEAD;
  const ushort* knh = args.kn[side] + (size_t)h * SGQ * DHEAD;
  const ushort* vth = args.vt[side] + (size_t)h * DHEAD * SGQ;
  ushort* cat = args.cat[side];
  const int r0w = qb * 128 + w * 32;

  s16x8 qf[4];
  #pragma unroll
  for (int s = 0; s < 4; ++s)
    qf[s] = *(const s16x8*)(qnh + (size_t)(r0w + l32) * DHEAD + s * 16 + hi * 8);

  const short one = (short)0x3F80;   // bf16 1.0
  const s16x8 ONES = {one, one, one, one, one, one, one, one};

  s16x8 sk[4], sv[2][2];
  auto prefetch = [&](int key0) {
    #pragma unroll
    for (int c = 0; c < 4; ++c) {
      int row = w * 32 + c * 8 + lr;
      sk[c] = *(const s16x8*)(knh + (size_t)(key0 + row) * DHEAD + l8 * 8);
    }
    #pragma unroll
    for (int c = 0; c < 2; ++c) {
      int vrow = w * 16 + c * 8 + lr;
      #pragma unroll
      for (int half = 0; half < 2; ++half)
        sv[c][half] = *(const s16x8*)(vth + (size_t)vrow * SGQ + key0 + (l8 + 8 * half) * 8);
    }
  };

  const f32x16 Z = {0,0,0,0,0,0,0,0,0,0,0,0,0,0,0,0};
  f32x16 o0 = Z, o1 = Z, osum = Z;
  const int krp = (l32 & 19) | ((l32 & 4) << 1) | ((l32 & 8) >> 1);  // swap bits 2<->3

  auto body = [&](int buf, int t) {
    #pragma unroll
    for (int c = 0; c < 4; ++c) {
      int row = w * 32 + c * 8 + lr;
      *(s16x8*)&Ksh[buf][row * 64 + ((l8 ^ SWX(row)) * 8)] = sk[c];
    }
    #pragma unroll
    for (int c = 0; c < 2; ++c) {
      int vrow = w * 16 + c * 8 + lr;
      #pragma unroll
      for (int half = 0; half < 2; ++half)
        *(s16x8*)&Vsh[buf][vrow * 128 + (((l8 + 8 * half) ^ S16(vrow)) * 8)] = sv[c][half];
    }
    asm volatile("s_waitcnt lgkmcnt(0)" ::: "memory");
    __builtin_amdgcn_s_barrier();
    asm volatile("" ::: "memory");
    if (t != 31) prefetch((t + 1) << 7);
    #pragma unroll
    for (int st = 0; st < 4; ++st) {
      const int kr = st * 32 + krp;
      const int rsw = SWX(kr);
      s16x8 ka[4];
      #pragma unroll
      for (int s = 0; s < 4; ++s)
        ka[s] = *(const s16x8*)&Ksh[buf][kr * 64 + (((s * 2 + hi) ^ rsw) * 8)];
      f32x16 S = Z;
      __builtin_amdgcn_s_setprio(1);
      #pragma unroll
      for (int s = 0; s < 4; ++s)
        S = __builtin_amdgcn_mfma_f32_32x32x16_bf16(ka[s], qf[s], S, 0, 0, 0);
      __builtin_amdgcn_s_setprio(0);
      // clip(-10,10) is a provable no-op; scores pre-scaled by log2e -> exp2 directly
      #pragma unroll
      for (int i = 0; i < 16; ++i) S[i] = exp2_hw(S[i]);
      uint u[8];
      #pragma unroll
      for (int j2 = 0; j2 < 8; ++j2) {
        uint r_;
        asm("v_cvt_pk_bf16_f32 %0, %1, %2" : "=v"(r_) : "v"(S[2 * j2]), "v"(S[2 * j2 + 1]));
        u[j2] = r_;
      }
      __builtin_amdgcn_s_setprio(1);
      #pragma unroll
      for (int slot = 0; slot < 2; ++slot) {
        u32x4 uv = {u[slot * 4 + 0], u[slot * 4 + 1], u[slot * 4 + 2], u[slot * 4 + 3]};
        s16x8 pf = __builtin_bit_cast(s16x8, uv);
        const int kcg = st * 4 + slot * 2 + hi;
        osum = __builtin_amdgcn_mfma_f32_32x32x16_bf16(pf, ONES, osum, 0, 0, 0);
        {
          const int vr = l32;
          s16x8 vb = *(const s16x8*)&Vsh[buf][vr * 128 + ((kcg ^ S16(vr)) * 8)];
          o0 = __builtin_amdgcn_mfma_f32_32x32x16_bf16(pf, vb, o0, 0, 0, 0);
        }
        {
          const int vr = 32 + l32;
          s16x8 vb = *(const s16x8*)&Vsh[buf][vr * 128 + ((kcg ^ S16(vr)) * 8)];
          o1 = __builtin_amdgcn_mfma_f32_32x32x16_bf16(pf, vb, o1, 0, 0, 0);
        }
      }
      __builtin_amdgcn_s_setprio(0);
    }
  };

  prefetch(0);
  for (int tt = 0; tt < 16; ++tt) {
    body(0, tt * 2);
    body(1, tt * 2 + 1);
  }

  #pragma unroll
  for (int r = 0; r < 16; ++r) {
    const int qr = (r & 3) + 8 * (r >> 2) + 4 * hi;
    float inv = 1.0f / osum[r];
    size_t base = (size_t)(r0w + qr) * 1024 + h * DHEAD + l32;
    cat[base] = f2bf(o0[r] * inv);
    cat[base + 32] = f2bf(o1[r] * inv);
  }
}

// ================= host ====================================================================
extern "C" void kernel_launch(void* const* d_in, const int* in_sizes, int n_in,
                              void* d_out, int out_size, void* d_ws, size_t ws_size,
                              hipStream_t stream) {
  const float* gene = (const float*)d_in[0];
  const float* drug = (const float*)d_in[1];
  const float* lng_g = (const float*)d_in[2];
  const float* lng_b = (const float*)d_in[3];
  const float* lnd_g = (const float*)d_in[4];
  const float* lnd_b = (const float*)d_in[5];
  const float* wgq = (const float*)d_in[6];  const float* bgq = (const float*)d_in[7];
  const float* wgk = (const float*)d_in[8];  const float* bgk = (const float*)d_in[9];
  const float* wgv = (const float*)d_in[10]; const float* bgv = (const float*)d_in[11];
  const float* wdq = (const float*)d_in[12]; const float* bdq = (const float*)d_in[13];
  const float* wdk = (const float*)d_in[14]; const float* bdk = (const float*)d_in[15];
  const float* wdv = (const float*)d_in[16]; const float* bdv = (const float*)d_in[17];
  const float* wo  = (const float*)d_in[18]; const float* bo  = (const float*)d_in[19];
  const float* wgg = (const float*)d_in[20]; const float* bgg = (const float*)d_in[21];
  const float* gg_g = (const float*)d_in[22]; const float* gg_b = (const float*)d_in[23];
  const float* wdg = (const float*)d_in[24]; const float* bdg = (const float*)d_in[25];
  const float* dg_g = (const float*)d_in[26]; const float* dg_b = (const float*)d_in[27];
  float* out = (float*)d_out;

  char* p = (char*)d_ws;
  size_t off = 0;
  auto alloc = [&](size_t bytes) { char* r = p + off; off = (off + bytes + 255) & ~(size_t)255; return r; };
  ushort* wT_gq = (ushort*)alloc(512 * 512 * 2);
  ushort* wT_gk = (ushort*)alloc(512 * 512 * 2);
  ushort* wT_gv = (ushort*)alloc(512 * 512 * 2);
  ushort* wT_dq = (ushort*)alloc(512 * 512 * 2);
  ushort* wT_dk = (ushort*)alloc(512 * 512 * 2);
  ushort* wT_dv = (ushort*)alloc(512 * 512 * 2);
  ushort* wT_o  = (ushort*)alloc(512 * 512 * 2);
  ushort* wT_gg = (ushort*)alloc(1024 * 512 * 2);
  ushort* wT_dg = (ushort*)alloc(1024 * 512 * 2);
  ushort* ng   = (ushort*)alloc((size_t)SGQ * 512 * 2);   // + nd = contiguous 8 MB
  ushort* nd   = (ushort*)alloc((size_t)SGQ * 512 * 2);
  ushort* catg = (ushort*)alloc((size_t)SGQ * 1024 * 2);
  ushort* catd = (ushort*)alloc((size_t)SGQ * 1024 * 2);
  ushort* qn_g = (ushort*)alloc((size_t)SGQ * 512 * 2);
  ushort* kn_g = (ushort*)alloc((size_t)SGQ * 512 * 2);
  ushort* qn_d = (ushort*)alloc((size_t)SGQ * 512 * 2);
  ushort* kn_d = (ushort*)alloc((size_t)SGQ * 512 * 2);
  ushort* vt_g = (ushort*)alloc((size_t)SGQ * 512 * 2);
  ushort* vt_d = (ushort*)alloc((size_t)SGQ * 512 * 2);
  // dead-buffer reuse after attention (qn/kn/vt dead) and after qkv (ng/nd dead):
  ushort* tmpF_g = qn_g;   // bf16 4 MB in dead qn_g
  ushort* tmpF_d = qn_d;
  ushort* tmpY_g = vt_g;
  ushort* tmpY_d = ng;

  dim3 blk(256);
  const float QSCALE = 0.125f * 1.4426950408889634f;  // head-scale * log2(e)

  PArgs pa;
  {
    const float* ws_[9] = {wgq, wgk, wgv, wdq, wdk, wdv, wo, wgg, wdg};
    ushort* wt_[9] = {wT_gq, wT_gk, wT_gv, wT_dq, wT_dk, wT_dv, wT_o, wT_gg, wT_dg};
    int k_[9] = {512, 512, 512, 512, 512, 512, 512, 1024, 1024};
    for (int i = 0; i < 9; ++i) { pa.w[i] = ws_[i]; pa.wt[i] = wt_[i]; pa.K[i] = k_[i]; }
    pa.x[0] = gene; pa.x[1] = drug;
    pa.gg[0] = lng_g; pa.gg[1] = lnd_g;
    pa.bb[0] = lng_b; pa.bb[1] = lnd_b;
    pa.normed[0] = ng; pa.normed[1] = nd;
    pa.cat[0] = catg; pa.cat[1] = catd;
  }
  prep_kernel<<<dim3(16, 32, 11), blk, 0, stream>>>(pa);

  GemmArgs qa;
  {
    const ushort* A_[6] = {ng, ng, catg + 512, nd, nd, catd + 512};
    const ushort* W_[6] = {wT_gq, wT_gk, wT_gv, wT_dq, wT_dk, wT_dv};
    const float* B_[6] = {bgq, bgk, bgv, bdq, bdk, bdv};
    ushort* D_[6] = {qn_g, kn_g, vt_g, qn_d, kn_d, vt_d};
    int lda_[6] = {512, 512, 1024, 512, 512, 1024};
    float sc_[6] = {QSCALE, 1.0f, 0.f, QSCALE, 1.0f, 0.f};
    int iv_[6] = {0, 0, 1, 0, 0, 1};
    for (int i = 0; i < 6; ++i) {
      qa.d[i].A = A_[i]; qa.d[i].Wt = W_[i]; qa.d[i].bias = B_[i];
      qa.d[i].dst = D_[i]; qa.d[i].emb = nullptr; qa.d[i].gate = nullptr;
      qa.d[i].lda = lda_[i]; qa.d[i].K = 512; qa.d[i].scale = sc_[i]; qa.d[i].isV = iv_[i];
    }
  }
  gemm_tiled<0><<<dim3(4, 32, 6), blk, 0, stream>>>(qa);

  AArgs aa;
  aa.qn[0] = qn_g; aa.qn[1] = qn_d;
  aa.kn[0] = kn_d; aa.kn[1] = kn_g;   // cross: gene-q attends drug-K/V, and vice versa
  aa.vt[0] = vt_d; aa.vt[1] = vt_g;
  aa.cat[0] = catg; aa.cat[1] = catd;
  attn_kernel<<<dim3(32, 8, 2), blk, 0, stream>>>(aa);

  // gate pre-LN GEMM (z=0,1) and ctx@wo+bo (z=2,3) in ONE dispatch, bf16 out
  GemmArgs ga;
  {
    const ushort* A_[4] = {catg, catd, catg, catd};
    const ushort* W_[4] = {wT_gg, wT_dg, wT_o, wT_o};
    const float* B_[4] = {bgg, bdg, bo, bo};
    ushort* D_[4] = {tmpF_g, tmpF_d, tmpY_g, tmpY_d};
    int k_[4] = {1024, 1024, 512, 512};
    for (int i = 0; i < 4; ++i) {
      ga.d[i].A = A_[i]; ga.d[i].Wt = W_[i]; ga.d[i].bias = B_[i];
      ga.d[i].dst = D_[i]; ga.d[i].emb = nullptr; ga.d[i].gate = nullptr;
      ga.d[i].lda = 1024; ga.d[i].K = k_[i]; ga.d[i].scale = 0.f; ga.d[i].isV = 0;
    }
  }
  gemm_tiled<1><<<dim3(4, 32, 4), blk, 0, stream>>>(ga);

  FArgs fa;
  fa.tF[0] = tmpF_g; fa.tF[1] = tmpF_d;
  fa.tY[0] = tmpY_g; fa.tY[1] = tmpY_d;
  fa.emb[0] = gene; fa.emb[1] = drug;
  fa.gamma[0] = gg_g; fa.gamma[1] = dg_g;
  fa.beta[0] = gg_b; fa.beta[1] = dg_b;
  fa.out[0] = out; fa.out[1] = out + (size_t)SGQ * 512;
  ln_sig_combine_kernel<<<dim3(1024, 2), blk, 0, stream>>>(fa);
}